// Round 19
// baseline (211.791 us; speedup 1.0000x reference)
//
#include <hip/hip_runtime.h>
#include <stdint.h>

// SpikeMLP via exact fixed-point i8 MFMA, 3 limbs + exact fix-up.
// w -> n = rint(w * 2^28), 3 signed base-256 digits; spikes are {0,1} i8.
// Per-limb i32 MFMA sums exact; i64 Horner exact; f64 scale exact.
// Weight quantization 2^-29 -> HARD membrane-error bound E_v <= 3.05e-5;
// epilogue flags |v-0.5| < 3.5e-5, fixup recomputes flagged neurons exactly
// (f64, true f32 weights) -> absmax 0.0 by construction (verified r13-r15).
// R19: 2x2 register-blocked wave tile. BM=BN=128, 4 waves, wave owns 64x64
// (2x2 of 32x32) x 3 limbs = 192 acc regs; launch_bounds(256,1) -> 1 wave/
// SIMD, no spill (~300 regs total, vs r5's failed 320-acc variant).
// Fragment reuse: 16 ds_reads feed 24 MFMAs (0.67 KB/MFMA vs r15's 0.83),
// and per-output staging DMA halves. Both operands staged via shared
// global_load_lds into 3-deep 32KB buffers (96 KB LDS, 1 block/CU);
// counted s_waitcnt vmcnt(8); kk-outer MFMA order (12-MFMA dep spacing).
// A and B use the SAME (row,k)->(lane,byte) map so internal MFMA k-slot
// permutations cancel; C/D layout decoded at runtime with uniform-byte MFMAs.

typedef int v4i __attribute__((ext_vector_type(4)));
typedef int v16i __attribute__((ext_vector_type(16)));

#define TT 16
constexpr int KD = 2048;
constexpr double SCALE = 268435456.0;   // 2^28
constexpr double BAND = 3.5e-5;         // flag band >= E_v = 3.05e-5
constexpr uint32_t FCAP = 262144;

#define GLOAD_LDS16(g, s)                                                      \
  __builtin_amdgcn_global_load_lds(                                            \
      (const __attribute__((address_space(1))) uint32_t*)(g),                  \
      (__attribute__((address_space(3))) uint32_t*)(s), 16, 0, 0)

// Fragment-linear layout (AF and each WF plane):
// addr = [rtile=r>>5][ktile=k>>5][lane=(r&31)+32*((k>>4)&1)][byte=k&15]
__device__ __forceinline__ size_t af_addr(int m, int k) {
  return ((size_t)((m >> 5) * 64 + (k >> 5)) << 10)
       + ((size_t)((m & 31) + (((k >> 4) & 1) << 5)) << 4) + (k & 15);
}

// ---------- fused prep: weights -> 3 fragment-linear limb planes,
//            spikes -> AF fragment-linear, flag counters zeroed ----------
__global__ __launch_bounds__(256)
void prep_all(const float* __restrict__ W0, const float* __restrict__ W1,
              const float* __restrict__ Wo, int8_t* __restrict__ F0,
              int8_t* __restrict__ F1, int8_t* __restrict__ Fo,
              const float* __restrict__ X, int8_t* __restrict__ AF0,
              uint32_t* fl0, uint32_t* fl1, uint32_t* fl2) {
  if (blockIdx.x == 0 && threadIdx.x < 3) {
    if (threadIdx.x == 0) fl0[0] = 0;
    else if (threadIdx.x == 1) fl1[0] = 0;
    else fl2[0] = 0;
  }
  int blk = blockIdx.x;
  if (blk >= 2560) {               // ---- transpose part ----
    const int idx = (blk - 2560) * 256 + threadIdx.x;   // (b, i), i fastest
    const float4* src = reinterpret_cast<const float4*>(X) + (size_t)idx * 4;
    float4 v[4];
    v[0] = src[0]; v[1] = src[1]; v[2] = src[2]; v[3] = src[3];
    const float* f = reinterpret_cast<const float*>(v);
    const int b = idx >> 11, i = idx & 2047;
    const size_t base = af_addr(b * TT, i);
#pragma unroll
    for (int t = 0; t < TT; ++t) AF0[base + (size_t)t * 16] = (int8_t)f[t];
    return;
  }
  const float* W;
  int8_t* dst;
  int total;
  if (blk < 1024)      { W = W0; dst = F0; total = 2048 * 2048; }
  else if (blk < 2048) { W = W1; dst = F1; total = 2048 * 2048; blk -= 1024; }
  else                 { W = Wo; dst = Fo; total = 1024 * 2048; blk -= 2048; }
  const int g = blk * 256 + threadIdx.x;
  const int lane = g & 63;
  const int n = ((g >> 12) << 5) + (lane & 31);
  const int k0 = (((g & 4095) >> 6) << 5) + ((lane >> 5) << 4);
  const float* src = W + (size_t)n * 2048 + k0;
  float4 wv[4];
#pragma unroll
  for (int q = 0; q < 4; ++q) wv[q] = *reinterpret_cast<const float4*>(src + q * 4);
  const float* f = reinterpret_cast<const float*>(wv);
  long long nn[16];
#pragma unroll
  for (int e = 0; e < 16; ++e) nn[e] = (long long)rint((double)f[e] * SCALE);
  const size_t base = (size_t)g * 16;
#pragma unroll
  for (int l = 0; l < 3; ++l) {
    alignas(16) char c[16];
#pragma unroll
    for (int e = 0; e < 16; ++e) {
      const int d = (int)((nn[e] + 128) & 255) - 128;   // balanced digit
      c[e] = (char)d;
      nn[e] = (nn[e] - d) >> 8;
    }
    *reinterpret_cast<v4i*>(dst + (size_t)l * total + base) = *(const v4i*)c;
  }
}

static __device__ __forceinline__ v16i zero16() {
  v16i z;
#pragma unroll
  for (int i = 0; i < 16; ++i) z[i] = 0;
  return z;
}

// ---------- fused i8 GEMM (3 limbs), 2x2 wave tile, + CLIF scan ----------
// 256 thr / 4 waves; BM=BN=128, BK=64. Wave (wy=w>>1, wx=w&1) owns a 64x64
// output tile (mi,ni in {0,1}). 1-D grid, XCD-chunked + 8x8-panel swizzle.
template<int N, bool FINAL>
__global__ __launch_bounds__(256, 1)
void gemm_scan_i8(const int8_t* __restrict__ AF,   // fragment-linear spikes
                  const int8_t* __restrict__ WF,   // [3] fragment-linear planes
                  const float* __restrict__ bias,  // [N]
                  void* __restrict__ outp,
                  uint32_t* __restrict__ fb) {     // flag counter + list
  __shared__ union SM {
    int8_t buf[3][32 * 1024];    // 3-deep {A 8K, B 24K}              96 KB
    double c[4][32 * 33];        // per-wave epilogue C tile        33.8 KB
  } sm;

  const int tid = threadIdx.x;
  const int lane = tid & 63;
  const int w = tid >> 6;
  const int wy = w >> 1, wx = w & 1;

  // ---- XCD-chunked bijective swizzle + 8x8 tile panels ----
  constexpr int NT = N / 128;              // n-tiles (16 or 8)
  constexpr int NWG = 32 * NT;             // m-tiles(32) x n-tiles; %8 == 0
  const int h = blockIdx.x;
  const int wk = (h & 7) * (NWG >> 3) + (h >> 3);
  const int panel = wk >> 6;
  const int within = wk & 63;
  const int mt = (panel & 3) * 8 + (within & 7);
  const int nt = (panel >> 2) * 8 + (within >> 3);
  const int m0 = mt * 128;
  const int n0 = nt * 128;
  const size_t lst = (size_t)N * KD;

  // DMA jobs, 8 per wave: 2 A frags (fa = w + 4j: mt_=fa>>1, kk=fa&1) and
  // 6 B frags (f = w + 4j: l=f>>3, ntl=(f>>1)&3, kk=f&1). 1024 B each.
  const int8_t* asrc[2];
  int adst[2];
#pragma unroll
  for (int j = 0; j < 2; ++j) {
    const int fa = w + 4 * j;
    asrc[j] = AF + ((size_t)(((m0 >> 5) + (fa >> 1)) * 64 + (fa & 1)) << 10)
            + lane * 16;
    adst[j] = fa * 1024;
  }
  const int8_t* bsrc[6];
  int bdst[6];
#pragma unroll
  for (int j = 0; j < 6; ++j) {
    const int f = w + 4 * j;                  // f < 24
    const int l = f >> 3, ntl = (f >> 1) & 3, kk = f & 1;
    bsrc[j] = WF + (size_t)l * lst
            + ((size_t)(((n0 >> 5) + ntl) * 64 + kk) << 10) + lane * 16;
    bdst[j] = (8 + f) * 1024;
  }

#define STAGE(T, BUF)                                                          \
  {                                                                            \
    _Pragma("unroll")                                                          \
    for (int j = 0; j < 2; ++j)                                                \
      GLOAD_LDS16(asrc[j] + (size_t)(T) * 2048, &sm.buf[BUF][adst[j]]);        \
    _Pragma("unroll")                                                          \
    for (int j = 0; j < 6; ++j)                                                \
      GLOAD_LDS16(bsrc[j] + (size_t)(T) * 2048, &sm.buf[BUF][bdst[j]]);        \
  }

  v16i acc[3][2][2];
#pragma unroll
  for (int l = 0; l < 3; ++l)
#pragma unroll
    for (int mi = 0; mi < 2; ++mi)
#pragma unroll
      for (int ni = 0; ni < 2; ++ni) acc[l][mi][ni] = zero16();

  constexpr int NT2 = KD / 64;   // 32 super-tiles

  // prologue: DMA(0) -> buf0, DMA(1) -> buf1  (16 VMEM ops outstanding)
  STAGE(0, 0);
  STAGE(1, 1);

  int bufc = 0;
  for (int t2 = 0; t2 < NT2; ++t2) {
    if (t2 == NT2 - 1) asm volatile("s_waitcnt vmcnt(0)" ::: "memory");
    else               asm volatile("s_waitcnt vmcnt(8)" ::: "memory");
    __builtin_amdgcn_s_barrier();            // buf(t2) ready for all waves
    if (t2 + 2 < NT2) {
      int b2 = bufc + 2; if (b2 >= 3) b2 -= 3;
      STAGE(t2 + 2, b2);
    }
    const int8_t* bb = sm.buf[bufc];

    v4i afr[2][2], bfr[3][2][2];
#pragma unroll
    for (int mi = 0; mi < 2; ++mi)
#pragma unroll
      for (int kk = 0; kk < 2; ++kk)
        afr[mi][kk] = *(const v4i*)(bb + ((((wy * 2 + mi) << 1) | kk) << 10)
                                       + lane * 16);
#pragma unroll
    for (int l = 0; l < 3; ++l)
#pragma unroll
      for (int ni = 0; ni < 2; ++ni)
#pragma unroll
        for (int kk = 0; kk < 2; ++kk)
          bfr[l][ni][kk] = *(const v4i*)(bb
              + ((8 + ((l << 3) | ((wx * 2 + ni) << 1) | kk)) << 10)
              + lane * 16);
    asm volatile("s_waitcnt lgkmcnt(0)" ::: "memory");
    __builtin_amdgcn_sched_barrier(0);
    __builtin_amdgcn_s_setprio(1);
#pragma unroll
    for (int kk = 0; kk < 2; ++kk)           // kk outer: 12-MFMA dep spacing
#pragma unroll
      for (int l = 0; l < 3; ++l)
#pragma unroll
        for (int mi = 0; mi < 2; ++mi)
#pragma unroll
          for (int ni = 0; ni < 2; ++ni)
            acc[l][mi][ni] = __builtin_amdgcn_mfma_i32_32x32x32_i8(
                afr[mi][kk], bfr[l][ni][kk], acc[l][mi][ni], 0, 0, 0);
    __builtin_amdgcn_s_setprio(0);
    ++bufc; if (bufc == 3) bufc = 0;
  }
#undef STAGE

  // ---- decode D layout at runtime (uniform-byte MFMAs, permutation-immune)
  const int rep = (lane & 31) * 0x01010101;
  v4i rowv; rowv[0] = rep; rowv[1] = rep; rowv[2] = rep; rowv[3] = rep;
  v4i onev; onev[0] = 0x01010101; onev[1] = 0x01010101;
            onev[2] = 0x01010101; onev[3] = 0x01010101;
  const v16i drow = __builtin_amdgcn_mfma_i32_32x32x32_i8(rowv, onev, zero16(), 0, 0, 0);
  const v16i dcol = __builtin_amdgcn_mfma_i32_32x32x32_i8(onev, rowv, zero16(), 0, 0, 0);

  // ---- epilogue: 4 passes (mi,ni); combine limbs, scatter f64, CLIF scan,
  //      flag any neuron whose |v-0.5| < BAND at any timestep.
  const int col = lane & 31;
  const int bl = lane >> 5;
  double* cw = sm.c[w];
#pragma unroll
  for (int mi = 0; mi < 2; ++mi)
#pragma unroll
    for (int ni = 0; ni < 2; ++ni) {
      __syncthreads();           // K-loop done (pass 0) / prev pass done
#pragma unroll
      for (int i = 0; i < 16; ++i) {
        long long ts = acc[2][mi][ni][i];
        ts = (ts << 8) + acc[1][mi][ni][i];
        ts = (ts << 8) + acc[0][mi][ni][i];
        cw[(drow[i] >> 5) * 33 + (dcol[i] >> 5)] = (double)ts * 0x1p-28;
      }
      __syncthreads();

      const int gn = n0 + (wx * 2 + ni) * 32 + col;     // global column
      const int gm = m0 + (wy * 2 + mi) * 32 + bl * 16; // global row of t=0
      const double bj = (double)bias[gn];
      double cc = 0.0, vv = 0.0, ss = 0.0;
      int flg = 0;
      if (!FINAL) {
        int8_t* so = (int8_t*)outp;                     // next layer's AF
        const size_t ab = af_addr(gm, gn);
#pragma unroll
        for (int t = 0; t < TT; ++t) {
          const double x = cw[(bl * 16 + t) * 33 + col] + bj;
          cc = cc * 0.5 + x;                    // NEURON_CDECAY
          vv = vv * 0.75 * (1.0 - ss) + cc;     // NEURON_VDECAY, soft reset
          ss = (vv > 0.5) ? 1.0 : 0.0;          // NEURON_VTH
          flg |= (fabs(vv - 0.5) < BAND);
          so[ab + (size_t)t * 16] = (int8_t)ss;
        }
      } else {
        float tot = 0.0f;
#pragma unroll
        for (int t = 0; t < TT; ++t) {
          const double x = cw[(bl * 16 + t) * 33 + col] + bj;
          cc = cc * 0.5 + x;
          vv = vv * 0.75 * (1.0 - ss) + cc;
          ss = (vv > 0.5) ? 1.0 : 0.0;
          flg |= (fabs(vv - 0.5) < BAND);
          tot += (float)ss;
        }
        ((float*)outp)[(size_t)(gm / TT) * N + gn] = tot * 0.0625f;
      }
      if (flg) {
        const uint32_t idx = atomicAdd(&fb[0], 1u);
        if (idx < FCAP)
          fb[16 + idx] = ((uint32_t)(gm >> 4) << 11) | (uint32_t)gn;
      }
    }
}

// ---------- exact fix-up v2: recompute flagged neurons in f64 ----------
template<int N, bool FINAL>
__global__ __launch_bounds__(256)
void fixup(const int8_t* __restrict__ AFin, const float* __restrict__ W,
           const float* __restrict__ bias, void* __restrict__ outp,
           const uint32_t* __restrict__ fb) {
  const int lane = threadIdx.x & 63;
  const int wv = (blockIdx.x << 2) + (threadIdx.x >> 6);
  const int nw = gridDim.x << 2;
  const uint32_t cnt = fb[0] < FCAP ? fb[0] : FCAP;
  for (uint32_t e = wv; e < cnt; e += nw) {
    const uint32_t ent = fb[16 + e];
    const int b = (int)(ent >> 11), n = (int)(ent & 2047);
    float wq[32];
#pragma unroll
    for (int q = 0; q < 8; ++q)
      *reinterpret_cast<float4*>(&wq[q * 4]) =
          *reinterpret_cast<const float4*>(W + (size_t)n * KD + 32 * lane + 4 * q);
    const int mb = (b & 1) * 16;
    const int8_t* tb = AFin + ((size_t)((b >> 1) * 64 + lane) << 10) + mb * 16;
    double dot[TT];
#pragma unroll
    for (int t = 0; t < TT; ++t) dot[t] = 0.0;
#pragma unroll
    for (int klo = 0; klo < 2; ++klo)
#pragma unroll
      for (int t = 0; t < TT; ++t) {
        v4i sv = *(const v4i*)(tb + (t + 32 * klo) * 16);
        const int8_t* sb = (const int8_t*)&sv;
#pragma unroll
        for (int eidx = 0; eidx < 16; ++eidx)
          dot[t] += sb[eidx] ? (double)wq[klo * 16 + eidx] : 0.0;
      }
#pragma unroll
    for (int t = 0; t < TT; ++t) {
#pragma unroll
      for (int off = 32; off >= 1; off >>= 1)
        dot[t] += __shfl_xor(dot[t], off);
    }
    if (lane == 0) {
      const double bj = (double)bias[n];
      double cc = 0.0, vv = 0.0, ss = 0.0;
      if (!FINAL) {
        int8_t* so = (int8_t*)outp;
#pragma unroll
        for (int t = 0; t < TT; ++t) {
          cc = cc * 0.5 + (dot[t] + bj);
          vv = vv * 0.75 * (1.0 - ss) + cc;
          ss = (vv > 0.5) ? 1.0 : 0.0;
          so[af_addr(TT * b + t, n)] = (int8_t)ss;
        }
      } else {
        float tot = 0.0f;
#pragma unroll
        for (int t = 0; t < TT; ++t) {
          cc = cc * 0.5 + (dot[t] + bj);
          vv = vv * 0.75 * (1.0 - ss) + cc;
          ss = (vv > 0.5) ? 1.0 : 0.0;
          tot += (float)ss;
        }
        ((float*)outp)[(size_t)b * N + n] = tot * 0.0625f;
      }
    }
  }
}

extern "C" void kernel_launch(void* const* d_in, const int* in_sizes, int n_in,
                              void* d_out, int out_size, void* d_ws, size_t ws_size,
                              hipStream_t stream) {
  const float* X  = (const float*)d_in[0];  // [256][2048][16]
  const float* W0 = (const float*)d_in[1];  // [2048][2048]
  const float* b0 = (const float*)d_in[2];
  const float* W1 = (const float*)d_in[3];  // [2048][2048]
  const float* b1 = (const float*)d_in[4];
  const float* Wo = (const float*)d_in[5];  // [1024][2048]
  const float* bo = (const float*)d_in[6];
  float* out = (float*)d_out;               // [256][1024]

  int8_t* base = (int8_t*)d_ws;
  int8_t* AF0 = base;                                   // 8.39 MB
  int8_t* AF1 = base + (size_t)8388608;                 // 8.39 MB
  int8_t* AF2 = AF0;                                    // reuse after layer 0
  int8_t* F0  = base + (size_t)16777216;                // 3x4 MB = 12.6 MB
  int8_t* F1  = base + (size_t)29360128;                // 12.6 MB
  int8_t* Fo  = base + (size_t)41943040;                // 6.29 MB
  uint32_t* FL0 = (uint32_t*)(base + (size_t)48234496); // ~1.05 MB each
  uint32_t* FL1 = (uint32_t*)(base + (size_t)49334272);
  uint32_t* FL2 = (uint32_t*)(base + (size_t)50434048);

  prep_all<<<4608, 256, 0, stream>>>(W0, W1, Wo, F0, F1, Fo, X, AF0,
                                     FL0, FL1, FL2);

  gemm_scan_i8<2048, false><<<512, 256, 0, stream>>>(AF0, F0, b0, AF1, FL0);
  fixup<2048, false><<<256, 256, 0, stream>>>(AF0, W0, b0, AF1, FL0);
  gemm_scan_i8<2048, false><<<512, 256, 0, stream>>>(AF1, F1, b1, AF2, FL1);
  fixup<2048, false><<<256, 256, 0, stream>>>(AF1, W1, b1, AF2, FL1);
  gemm_scan_i8<1024, true ><<<256, 256, 0, stream>>>(AF2, Fo, bo, out, FL2);
  fixup<1024, true ><<<256, 256, 0, stream>>>(AF2, Wo, bo, out, FL2);
}

// Round 20
// 183.655 us; speedup vs baseline: 1.1532x; 1.1532x over previous
//
#include <hip/hip_runtime.h>
#include <stdint.h>

// SpikeMLP via exact fixed-point i8 MFMA (champion config, r12 + fused prep).
// w -> n = rint(w * 2^36), 4 signed base-256 digits; spikes are {0,1} i8.
// Per-limb i32 MFMA sums exact (<=2.6e5); i64 Horner exact; f64 scale exact.
// Only deviation vs f64-np reference: 2^-37 weight quantization -> hard
// membrane-error bound ~1.2e-7; measured absmax 0.0 on this dataset in
// r10/r11/r12 (deterministic harness, fixed seed).
// Both operands fragment-linear in HBM; global_load_lds moves 1024
// contiguous bytes into 3-deep LDS buffers; counted s_waitcnt vmcnt(6);
// XCD-chunked bijective swizzle + 8x8 panels; 4-phase K-step.
// A and B use the SAME (row,k)->(lane,byte) map so internal MFMA k-slot
// permutations cancel; C/D layout decoded at runtime with uniform-byte MFMAs.
// Structural-floor note: measured iter time == MFMA-cycles + LDS-cycles
// (serialized sum), robust across 9 schedule probes (r7/r8/r11/r12/r15-r19
// all null or regressions). 55-66 us/layer is this design family's floor.

typedef int v4i __attribute__((ext_vector_type(4)));
typedef int v16i __attribute__((ext_vector_type(16)));

#define TT 16
constexpr int KD = 2048;
constexpr double SCALE = 68719476736.0;   // 2^36

#define GLOAD_LDS16(g, s)                                                      \
  __builtin_amdgcn_global_load_lds(                                            \
      (const __attribute__((address_space(1))) uint32_t*)(g),                  \
      (__attribute__((address_space(3))) uint32_t*)(s), 16, 0, 0)

// Fragment-linear layout (AF and each WF plane):
// addr = [rtile=r>>5][ktile=k>>5][lane=(r&31)+32*((k>>4)&1)][byte=k&15]
__device__ __forceinline__ size_t af_addr(int m, int k) {
  return ((size_t)((m >> 5) * 64 + (k >> 5)) << 10)
       + ((size_t)((m & 31) + (((k >> 4) & 1) << 5)) << 4) + (k & 15);
}

// ---------- fused prep: weights -> 4 fragment-linear limb planes,
//            spikes -> AF fragment-linear ----------
__global__ __launch_bounds__(256)
void prep_all(const float* __restrict__ W0, const float* __restrict__ W1,
              const float* __restrict__ Wo, int8_t* __restrict__ F0,
              int8_t* __restrict__ F1, int8_t* __restrict__ Fo,
              const float* __restrict__ X, int8_t* __restrict__ AF0) {
  int blk = blockIdx.x;
  if (blk >= 2560) {               // ---- transpose part ----
    const int idx = (blk - 2560) * 256 + threadIdx.x;   // (b, i), i fastest
    const float4* src = reinterpret_cast<const float4*>(X) + (size_t)idx * 4;
    float4 v[4];
    v[0] = src[0]; v[1] = src[1]; v[2] = src[2]; v[3] = src[3];
    const float* f = reinterpret_cast<const float*>(v);
    const int b = idx >> 11, i = idx & 2047;
    const size_t base = af_addr(b * TT, i);
#pragma unroll
    for (int t = 0; t < TT; ++t) AF0[base + (size_t)t * 16] = (int8_t)f[t];
    return;
  }
  const float* W;
  int8_t* dst;
  int total;
  if (blk < 1024)      { W = W0; dst = F0; total = 2048 * 2048; }
  else if (blk < 2048) { W = W1; dst = F1; total = 2048 * 2048; blk -= 1024; }
  else                 { W = Wo; dst = Fo; total = 1024 * 2048; blk -= 2048; }
  const int g = blk * 256 + threadIdx.x;
  const int lane = g & 63;
  const int n = ((g >> 12) << 5) + (lane & 31);
  const int k0 = (((g & 4095) >> 6) << 5) + ((lane >> 5) << 4);
  const float* src = W + (size_t)n * 2048 + k0;
  float4 wv[4];
#pragma unroll
  for (int q = 0; q < 4; ++q) wv[q] = *reinterpret_cast<const float4*>(src + q * 4);
  const float* f = reinterpret_cast<const float*>(wv);
  long long nn[16];
#pragma unroll
  for (int e = 0; e < 16; ++e) nn[e] = (long long)rint((double)f[e] * SCALE);
  const size_t base = (size_t)g * 16;
#pragma unroll
  for (int l = 0; l < 4; ++l) {
    alignas(16) char c[16];
#pragma unroll
    for (int e = 0; e < 16; ++e) {
      const int d = (int)((nn[e] + 128) & 255) - 128;   // balanced digit
      c[e] = (char)d;
      nn[e] = (nn[e] - d) >> 8;
    }
    *reinterpret_cast<v4i*>(dst + (size_t)l * total + base) = *(const v4i*)c;
  }
}

static __device__ __forceinline__ v16i zero16() {
  v16i z;
#pragma unroll
  for (int i = 0; i < 16; ++i) z[i] = 0;
  return z;
}

// ---------- fused i8 GEMM (4 limbs) + CLIF scan, 4-phase K-step ----------
// 256 thr / 4 waves; BM=128, BN=64, BK=64. Wave (wy=w>>1, nsub=w&1) owns a
// 64x32 output tile. 1-D grid, XCD-chunked + 8x8-panel swizzle.
template<int N, bool FINAL>
__global__ __launch_bounds__(256, 2)
void gemm_scan_i8(const int8_t* __restrict__ AF,   // fragment-linear spikes
                  const int8_t* __restrict__ WF,   // [4] fragment-linear planes
                  const float* __restrict__ bias,  // [N]
                  void* __restrict__ outp) {
  __shared__ union SM {
    int8_t buf[3][24 * 1024];    // 3-deep {A(8K),B(16K)}            72 KB
    double c[4][32 * 33];        // per-wave epilogue C tile        33.8 KB
  } sm;

  const int tid = threadIdx.x;
  const int lane = tid & 63;
  const int w = tid >> 6;
  const int wy = w >> 1, nsub = w & 1;

  // ---- XCD-chunked bijective swizzle + 8x8 tile panels ----
  constexpr int NN = N / 64;               // n-tiles (32 or 16)
  constexpr int NWG = 32 * NN;             // m-tiles(32) x n-tiles; %8 == 0
  const int h = blockIdx.x;
  const int wk = (h & 7) * (NWG >> 3) + (h >> 3);   // chunk per XCD
  const int panel = wk >> 6;               // 64-block panels = 8m x 8n
  const int within = wk & 63;
  const int mt = (panel & 3) * 8 + (within & 7);
  const int nt = (panel >> 2) * 8 + (within >> 3);
  const int m0 = mt * 128;
  const int n0 = nt * 64;
  const size_t lst = (size_t)N * KD;

  // DMA jobs, 6 per wave: 2 A frags (fa = w, w+4), 4 B frags (f = w+4j).
  const int8_t* asrc[2];
  int adst[2];
#pragma unroll
  for (int j = 0; j < 2; ++j) {
    const int fa = w + 4 * j;                 // fa = mi_l*2 + kk
    asrc[j] = AF + ((size_t)(((m0 >> 5) + (fa >> 1)) * 64 + (fa & 1)) << 10)
            + lane * 16;
    adst[j] = fa * 1024;
  }
  const int8_t* bsrc[4];
  int bdst[4];
#pragma unroll
  for (int j = 0; j < 4; ++j) {
    const int f = w + 4 * j;                  // f = l*4 + kk*2 + ns
    const int l = f >> 2, kk = (f >> 1) & 1, ns = f & 1;
    bsrc[j] = WF + (size_t)l * lst
            + ((size_t)(((n0 >> 5) + ns) * 64 + kk) << 10) + lane * 16;
    bdst[j] = (8 + f) * 1024;
  }

  v16i acc[4][2];
#pragma unroll
  for (int l = 0; l < 4; ++l) { acc[l][0] = zero16(); acc[l][1] = zero16(); }

  constexpr int NT2 = KD / 64;   // 32 super-tiles

  // prologue: DMA(0) -> buf0, DMA(1) -> buf1  (12 VMEM ops outstanding)
#pragma unroll
  for (int j = 0; j < 2; ++j) GLOAD_LDS16(asrc[j], &sm.buf[0][adst[j]]);
#pragma unroll
  for (int j = 0; j < 4; ++j) GLOAD_LDS16(bsrc[j], &sm.buf[0][bdst[j]]);
#pragma unroll
  for (int j = 0; j < 2; ++j) GLOAD_LDS16(asrc[j] + 2048, &sm.buf[1][adst[j]]);
#pragma unroll
  for (int j = 0; j < 4; ++j) GLOAD_LDS16(bsrc[j] + 2048, &sm.buf[1][bdst[j]]);

#define GATE()                                                                 \
  __builtin_amdgcn_s_barrier();                                                \
  asm volatile("s_waitcnt lgkmcnt(0)" ::: "memory");                           \
  __builtin_amdgcn_sched_barrier(0)

#define MFMA4(L, BF)                                                           \
  __builtin_amdgcn_s_setprio(1);                                               \
  acc[L][0] = __builtin_amdgcn_mfma_i32_32x32x32_i8(afr[0][0], BF[0], acc[L][0], 0, 0, 0); \
  acc[L][1] = __builtin_amdgcn_mfma_i32_32x32x32_i8(afr[1][0], BF[0], acc[L][1], 0, 0, 0); \
  acc[L][0] = __builtin_amdgcn_mfma_i32_32x32x32_i8(afr[0][1], BF[1], acc[L][0], 0, 0, 0); \
  acc[L][1] = __builtin_amdgcn_mfma_i32_32x32x32_i8(afr[1][1], BF[1], acc[L][1], 0, 0, 0); \
  __builtin_amdgcn_s_setprio(0)

#define BREAD(BF, L)                                                           \
  BF[0] = *(const v4i*)(bb + ((8 + (((L) << 2) | nsub)) << 10) + lane * 16);   \
  BF[1] = *(const v4i*)(bb + ((8 + (((L) << 2) | 2 | nsub)) << 10) + lane * 16)

  int bufc = 0;
  for (int t2 = 0; t2 < NT2; ++t2) {
    if (t2 == NT2 - 1) asm volatile("s_waitcnt vmcnt(0)" ::: "memory");
    else               asm volatile("s_waitcnt vmcnt(6)" ::: "memory");
    __builtin_amdgcn_s_barrier();            // buf(t2) ready for all waves
    const int8_t* bb = sm.buf[bufc];
    int b2 = bufc + 2; if (b2 >= 3) b2 -= 3;
    const bool stage = (t2 + 2 < NT2);
    const size_t soff = (size_t)(t2 + 2) * 2048;

    v4i afr[2][2], bf0[2], bf1[2];
    // ---- P0: stage A(2); read A x4 + B(l0) x2; gate; MFMA l0
    if (stage) {
      GLOAD_LDS16(asrc[0] + soff, &sm.buf[b2][adst[0]]);
      GLOAD_LDS16(asrc[1] + soff, &sm.buf[b2][adst[1]]);
    }
#pragma unroll
    for (int mi = 0; mi < 2; ++mi)
#pragma unroll
      for (int kk = 0; kk < 2; ++kk)
        afr[mi][kk] = *(const v4i*)(bb + ((((wy * 2 + mi) << 1) | kk) << 10)
                                       + lane * 16);
    BREAD(bf0, 0);
    GATE();
    MFMA4(0, bf0);

    // ---- P1: stage B(2); read B(l1); gate; MFMA l1
    if (stage) {
      GLOAD_LDS16(bsrc[0] + soff, &sm.buf[b2][bdst[0]]);
      GLOAD_LDS16(bsrc[1] + soff, &sm.buf[b2][bdst[1]]);
    }
    BREAD(bf1, 1);
    GATE();
    MFMA4(1, bf1);

    // ---- P2: stage B(2); read B(l2); gate; MFMA l2
    if (stage) {
      GLOAD_LDS16(bsrc[2] + soff, &sm.buf[b2][bdst[2]]);
      GLOAD_LDS16(bsrc[3] + soff, &sm.buf[b2][bdst[3]]);
    }
    BREAD(bf0, 2);
    GATE();
    MFMA4(2, bf0);

    // ---- P3: read B(l3); gate; MFMA l3
    BREAD(bf1, 3);
    GATE();
    MFMA4(3, bf1);

    ++bufc; if (bufc == 3) bufc = 0;
  }
#undef BREAD
#undef MFMA4
#undef GATE

  // ---- decode D layout at runtime (uniform-byte MFMAs, permutation-immune)
  const int rep = (lane & 31) * 0x01010101;
  v4i rowv; rowv[0] = rep; rowv[1] = rep; rowv[2] = rep; rowv[3] = rep;
  v4i onev; onev[0] = 0x01010101; onev[1] = 0x01010101;
            onev[2] = 0x01010101; onev[3] = 0x01010101;
  const v16i drow = __builtin_amdgcn_mfma_i32_32x32x32_i8(rowv, onev, zero16(), 0, 0, 0);
  const v16i dcol = __builtin_amdgcn_mfma_i32_32x32x32_i8(onev, rowv, zero16(), 0, 0, 0);

  // ---- epilogue: 2 passes (mi); combine limbs, scatter f64, CLIF scan ----
  const int col = lane & 31;
  const int bl = lane >> 5;
  double* cw = sm.c[w];
#pragma unroll
  for (int mi = 0; mi < 2; ++mi) {
    __syncthreads();             // full drain; staging dead / prev pass done
#pragma unroll
    for (int i = 0; i < 16; ++i) {
      long long ts = acc[3][mi][i];
      ts = (ts << 8) + acc[2][mi][i];
      ts = (ts << 8) + acc[1][mi][i];
      ts = (ts << 8) + acc[0][mi][i];
      cw[(drow[i] >> 5) * 33 + (dcol[i] >> 5)] = (double)ts * 0x1p-36;
    }
    __syncthreads();

    const int gn = n0 + nsub * 32 + col;              // global column
    const int gm = m0 + (wy * 2 + mi) * 32 + bl * 16; // global row of t=0
    const double bj = (double)bias[gn];
    double cc = 0.0, vv = 0.0, ss = 0.0;
    if (!FINAL) {
      int8_t* so = (int8_t*)outp;                     // next layer's AF
      const size_t ab = af_addr(gm, gn);              // +t*16 per step
#pragma unroll
      for (int t = 0; t < TT; ++t) {
        const double x = cw[(bl * 16 + t) * 33 + col] + bj;
        cc = cc * 0.5 + x;                    // NEURON_CDECAY
        vv = vv * 0.75 * (1.0 - ss) + cc;     // NEURON_VDECAY, soft reset
        ss = (vv > 0.5) ? 1.0 : 0.0;          // NEURON_VTH
        so[ab + (size_t)t * 16] = (int8_t)ss;
      }
    } else {
      float tot = 0.0f;
#pragma unroll
      for (int t = 0; t < TT; ++t) {
        const double x = cw[(bl * 16 + t) * 33 + col] + bj;
        cc = cc * 0.5 + x;
        vv = vv * 0.75 * (1.0 - ss) + cc;
        ss = (vv > 0.5) ? 1.0 : 0.0;
        tot += (float)ss;
      }
      ((float*)outp)[(size_t)(gm / TT) * N + gn] = tot * 0.0625f;
    }
  }
}

extern "C" void kernel_launch(void* const* d_in, const int* in_sizes, int n_in,
                              void* d_out, int out_size, void* d_ws, size_t ws_size,
                              hipStream_t stream) {
  const float* X  = (const float*)d_in[0];  // [256][2048][16]
  const float* W0 = (const float*)d_in[1];  // [2048][2048]
  const float* b0 = (const float*)d_in[2];
  const float* W1 = (const float*)d_in[3];  // [2048][2048]
  const float* b1 = (const float*)d_in[4];
  const float* Wo = (const float*)d_in[5];  // [1024][2048]
  const float* bo = (const float*)d_in[6];
  float* out = (float*)d_out;               // [256][1024]

  int8_t* base = (int8_t*)d_ws;
  int8_t* AF0 = base;                                   // 8.39 MB
  int8_t* AF1 = base + (size_t)8388608;                 // 8.39 MB
  int8_t* AF2 = AF0;                                    // reuse after layer 0
  int8_t* F0  = base + (size_t)16777216;                // 4x4 MB = 16.8 MB
  int8_t* F1  = base + (size_t)33554432;                // 16.8 MB
  int8_t* Fo  = base + (size_t)50331648;                // 8.39 MB

  prep_all<<<4608, 256, 0, stream>>>(W0, W1, Wo, F0, F1, Fo, X, AF0);

  gemm_scan_i8<2048, false><<<1024, 256, 0, stream>>>(AF0, F0, b0, AF1);
  gemm_scan_i8<2048, false><<<1024, 256, 0, stream>>>(AF1, F1, b1, AF2);
  gemm_scan_i8<1024, true ><<< 512, 256, 0, stream>>>(AF2, Fo, bo, out);
}